// Round 1
// baseline (294.679 us; speedup 1.0000x reference)
//
#include <hip/hip_runtime.h>
#include <cstdint>

#define TTOK 16384
#define HD   1024
#define NE   8
#define NDE  128
#define NDS  512
#define NC1  1536   // concat fc1 rows: E*DE routed + DS shared
#define KC2  1536   // concat fc2 cols in W2cat
#define NPAIR 28
#define MAXT  96    // max 256-row M-tiles over pair segments
#define PREPB 3080
#define GATEB 1024  // 16 tokens per block
#define NH    768   // grouped hidden: 128(e1)+128(e2)+512(shared)

typedef float  f32x4  __attribute__((ext_vector_type(4)));
typedef __bf16 bf16x8 __attribute__((ext_vector_type(8)));

__device__ __forceinline__ unsigned short f2bf(float f) {
  unsigned int u = __float_as_uint(f);
  u += 0x7fffu + ((u >> 16) & 1u);   // RNE; inputs finite
  return (unsigned short)(u >> 16);
}

__device__ __forceinline__ void gl2lds16(const void* gp, void* lp) {
  void* g0 = const_cast<void*>(gp);
  __builtin_amdgcn_global_load_lds((__attribute__((address_space(1))) void*)g0,
                                   (__attribute__((address_space(3))) void*)lp,
                                   16, 0, 0);
}

__device__ __forceinline__ void barx() {
  asm volatile("" ::: "memory");
  __builtin_amdgcn_s_barrier();
  asm volatile("" ::: "memory");
}

// ---- 8-phase GEMM phase helpers (256x256 tile, BK=64, 8 waves, wave tile 128x64) ----
// Quadrant Q: MH = Q>>1 picks mi 0-3 / 4-7, NHF = Q&1 picks ni 0-1 / 2-3.
template<int Q>
__device__ __forceinline__ void phase_reads(const unsigned short* Ab, const unsigned short* Bb,
                                            int bs, int a0, int b0,
                                            bf16x8 (&av)[4][2], bf16x8 (&bv)[2][2]) {
  constexpr int MH = Q >> 1, NHF = Q & 1;
  if constexpr (NHF == 0) {
#pragma unroll
    for (int m = 0; m < 4; ++m) {
      const int ao = a0 + (MH * 4 + m) * 1024;
      av[m][0] = *(const bf16x8*)(Ab + bs + ao);
      av[m][1] = *(const bf16x8*)(Ab + bs + (ao ^ 32));
    }
  }
#pragma unroll
  for (int n = 0; n < 2; ++n) {
    const int bo = b0 + (NHF * 2 + n) * 1024;
    bv[n][0] = *(const bf16x8*)(Bb + bs + bo);
    bv[n][1] = *(const bf16x8*)(Bb + bs + (bo ^ 32));
  }
}

template<int Q>
__device__ __forceinline__ void phase_mfma(bf16x8 (&av)[4][2], bf16x8 (&bv)[2][2],
                                           f32x4 (&acc)[8][4]) {
  constexpr int MH = Q >> 1, NHF = Q & 1;
  __builtin_amdgcn_s_setprio(1);
#pragma unroll
  for (int ks = 0; ks < 2; ++ks)
#pragma unroll
    for (int m = 0; m < 4; ++m)
#pragma unroll
      for (int n = 0; n < 2; ++n)
        acc[MH * 4 + m][NHF * 2 + n] = __builtin_amdgcn_mfma_f32_16x16x32_bf16(
            av[m][ks], bv[n][ks], acc[MH * 4 + m][NHF * 2 + n], 0, 0, 0);
  __builtin_amdgcn_s_setprio(0);
}

// Phase: ds_read quadrant ops || issue one half-tile prefetch -> barrier -> lgkm(0) -> MFMA -> barrier
#define PH(Q, BH, STG, VMW) do {                                    \
    phase_reads<Q>(AsB, BsB, (BH) * 16384, a0, b0, av, bv);         \
    STG;                                                            \
    VMW;                                                            \
    barx();                                                         \
    asm volatile("s_waitcnt lgkmcnt(0)" ::: "memory");              \
    __builtin_amdgcn_sched_barrier(0);                              \
    phase_mfma<Q>(av, bv, acc);                                     \
    barx();                                                         \
  } while (0)

// ---------------- K1: fused weight prep + gate (unchanged) ----------------
__global__ __launch_bounds__(256) void prep_gate(
    const float* __restrict__ x, const float* __restrict__ Wg,
    const float* __restrict__ W1, const float* __restrict__ Ws1,
    const float* __restrict__ W2, const float* __restrict__ Ws2,
    const float* __restrict__ b1, const float* __restrict__ bs1,
    unsigned short* __restrict__ W1cat, unsigned short* __restrict__ W2cat,
    float* __restrict__ bias1, unsigned short* __restrict__ xbf,
    float2* __restrict__ wpair, int* __restrict__ pid) {
  if (blockIdx.x < PREPB) {
    const int total = NC1 * HD + HD * KC2 + NC1;
    for (int idx = blockIdx.x * 256 + threadIdx.x; idx < total; idx += PREPB * 256) {
      if (idx < NC1 * HD) {
        int r = idx >> 10, k = idx & 1023;
        float v = (r < 1024) ? W1[idx] : Ws1[(size_t)(r - 1024) * HD + k];
        W1cat[idx] = f2bf(v);
      } else if (idx < NC1 * HD + HD * KC2) {
        int i2 = idx - NC1 * HD;
        int h = i2 / KC2;
        int j = i2 - h * KC2;
        float v = (j < 1024) ? W2[(size_t)((j >> 7) * HD + h) * NDE + (j & 127)]
                             : Ws2[(size_t)h * NDS + (j - 1024)];
        W2cat[i2] = f2bf(v);
      } else {
        int r = idx - (NC1 * HD + HD * KC2);
        bias1[r] = (r < 1024) ? b1[r] : bs1[r - 1024];
      }
    }
    return;
  }
  // ---- gate: block handles 16 tokens ----
  __shared__ float part[16 * 8 * 64];
  __shared__ float lgs[128];

  const int tid  = threadIdx.x;
  const int lane = tid & 63;
  const int wv   = tid >> 6;
  const int g    = blockIdx.x - PREPB;
  const int tokb = g * 16 + wv * 4;

  const float* xr = x + (size_t)tokb * HD + lane * 16;
  float4 xv[4][4];
#pragma unroll
  for (int t = 0; t < 4; ++t)
#pragma unroll
    for (int c = 0; c < 4; ++c)
      xv[t][c] = ((const float4*)(xr + (size_t)t * HD))[c];

#pragma unroll
  for (int t = 0; t < 4; ++t) {
    unsigned short* xo = xbf + (size_t)(tokb + t) * HD + lane * 16;
    union { unsigned short us[8]; uint4 v; } pk;
    pk.us[0] = f2bf(xv[t][0].x); pk.us[1] = f2bf(xv[t][0].y);
    pk.us[2] = f2bf(xv[t][0].z); pk.us[3] = f2bf(xv[t][0].w);
    pk.us[4] = f2bf(xv[t][1].x); pk.us[5] = f2bf(xv[t][1].y);
    pk.us[6] = f2bf(xv[t][1].z); pk.us[7] = f2bf(xv[t][1].w);
    ((uint4*)xo)[0] = pk.v;
    pk.us[0] = f2bf(xv[t][2].x); pk.us[1] = f2bf(xv[t][2].y);
    pk.us[2] = f2bf(xv[t][2].z); pk.us[3] = f2bf(xv[t][2].w);
    pk.us[4] = f2bf(xv[t][3].x); pk.us[5] = f2bf(xv[t][3].y);
    pk.us[6] = f2bf(xv[t][3].z); pk.us[7] = f2bf(xv[t][3].w);
    ((uint4*)xo)[1] = pk.v;
  }

  float p[4][8];
#pragma unroll
  for (int t = 0; t < 4; ++t)
#pragma unroll
    for (int e = 0; e < 8; ++e) p[t][e] = 0.f;
#pragma unroll
  for (int e = 0; e < 8; ++e) {
    const float4* wr = (const float4*)(Wg + (size_t)e * HD + lane * 16);
    float4 w0 = wr[0], w1 = wr[1], w2 = wr[2], w3 = wr[3];
#pragma unroll
    for (int t = 0; t < 4; ++t) {
      p[t][e] = w0.x * xv[t][0].x + w0.y * xv[t][0].y + w0.z * xv[t][0].z + w0.w * xv[t][0].w +
                w1.x * xv[t][1].x + w1.y * xv[t][1].y + w1.z * xv[t][1].z + w1.w * xv[t][1].w +
                w2.x * xv[t][2].x + w2.y * xv[t][2].y + w2.z * xv[t][2].z + w2.w * xv[t][2].w +
                w3.x * xv[t][3].x + w3.y * xv[t][3].y + w3.z * xv[t][3].z + w3.w * xv[t][3].w;
    }
  }
#pragma unroll
  for (int t = 0; t < 4; ++t)
#pragma unroll
    for (int e = 0; e < 8; ++e) {
      int j = (wv * 4 + t) * 8 + e;
      part[j * 64 + ((lane + 4 * j) & 63)] = p[t][e];
    }
  __syncthreads();

  if (tid < 128) {
    float s = 0.f;
#pragma unroll
    for (int m = 0; m < 16; ++m) {
      int kk = (4 * m + 4 * tid) & 63;
      float4 v = *(const float4*)&part[tid * 64 + kk];
      s += v.x + v.y + v.z + v.w;
    }
    lgs[tid] = s;
  }
  __syncthreads();

  if (tid < 16) {
    float lg[8];
#pragma unroll
    for (int e = 0; e < 8; ++e) lg[e] = lgs[tid * 8 + e];
    int i1 = 0; float m1 = lg[0];
#pragma unroll
    for (int e = 1; e < 8; ++e) { if (lg[e] > m1) { m1 = lg[e]; i1 = e; } }
    int i2 = -1; float m2 = -3.4e38f;
#pragma unroll
    for (int e = 0; e < 8; ++e) { if (e != i1 && lg[e] > m2) { m2 = lg[e]; i2 = e; } }
    float Z = 0.f;
#pragma unroll
    for (int e = 0; e < 8; ++e) Z += expf(lg[e] - m1);
    float s1 = 1.f / Z;
    float s2 = expf(m2 - m1) / Z;
    float dn = s1 + s2 + 1e-20f;
    float w1 = s1 / dn, w2 = s2 / dn;
    int ef, es; float wf, wsx;
    if (i1 < i2) { ef = i1; es = i2; wf = w1; wsx = w2; }
    else         { ef = i2; es = i1; wf = w2; wsx = w1; }
    int pq = ef * 7 - (ef * (ef - 1)) / 2 + (es - ef - 1);
    int t = g * 16 + tid;
    wpair[t] = make_float2(wf, wsx);
    pid[t] = pq;
  }
}

// ---------------- K2: atomic-free routing (256-row tiles) ----------------
__global__ __launch_bounds__(256) void route_scan(const int* __restrict__ pid,
                                                  int* __restrict__ perm,
                                                  int4* __restrict__ tiletab,
                                                  int* __restrict__ ntct) {
  __shared__ int hist[256 * 29];
  __shared__ int totals[NPAIR];
  __shared__ int spre[256];
  const int p   = blockIdx.x;
  const int tid = threadIdx.x;
#pragma unroll
  for (int q = 0; q < 29; ++q) hist[tid * 29 + q] = 0;
  __syncthreads();
  for (int k = 0; k < 64; ++k) {
    int q = pid[tid + (k << 8)];
    hist[tid * 29 + q]++;
  }
  __syncthreads();
  if (tid < NPAIR) {
    int s = 0;
    for (int i = 0; i < 256; ++i) s += hist[i * 29 + tid];
    totals[tid] = s;
  }
  __syncthreads();
  const int mycnt = hist[tid * 29 + p];
  spre[tid] = mycnt;
  __syncthreads();
  for (int d = 1; d < 256; d <<= 1) {
    int add = (tid >= d) ? spre[tid - d] : 0;
    __syncthreads();
    spre[tid] += add;
    __syncthreads();
  }
  int estart = 0, tstart = 0;
  for (int q = 0; q < p; ++q) { estart += totals[q]; tstart += (totals[q] + 255) >> 8; }
  const int cp = totals[p];
  const int nt = (cp + 255) >> 8;
  if (p == NPAIR - 1 && tid == 0) ntct[0] = tstart + nt;
  for (int k = tid; k < nt; k += 256) {
    int4 e;
    e.x = p;
    e.y = estart + (k << 8);
    e.z = min(256, cp - (k << 8));
    e.w = (tstart + k) << 8;   // hbase in rows
    tiletab[tstart + k] = e;
  }
  int wr = estart + spre[tid] - mycnt;
  for (int k = 0; k < 64; ++k) {
    int t = tid + (k << 8);
    if (pid[t] == p) perm[wr++] = t;
  }
}

// ---------------- G1: grouped fc1, 256x256 tile, 8-phase pipeline ----------------
__global__ __launch_bounds__(512, 2) void moe_fc1(
    const unsigned short* __restrict__ xbf, const unsigned short* __restrict__ W1cat,
    const int* __restrict__ perm, const float2* __restrict__ wpair,
    const float* __restrict__ bias1, const int4* __restrict__ tiletab,
    const int* __restrict__ ntct, unsigned short* __restrict__ Hbuf) {
  const int L   = blockIdx.x;
  const int xcd = L & 7;
  const int s   = L >> 3;
  const int mg  = s / 3;
  const int nn  = s - mg * 3;       // 0: routed e1|e2, 1: shared[0:256), 2: shared[256:512)
  const int mt  = xcd + (mg << 3);
  if (mt >= ntct[0]) return;
  const int4 tt = tiletab[mt];
  const int eoff = tt.y, valid = tt.z, hbase = tt.w;
  int ef = 0, rem = tt.x;
  while (rem >= 7 - ef) { rem -= 7 - ef; ef++; }
  const int es = ef + 1 + rem;

  __shared__ __align__(16) unsigned short As[2 * 16384];   // 64 KiB (2 bufs x 256x64)
  __shared__ __align__(16) unsigned short Bs[2 * 16384];   // 64 KiB

  const int tid  = threadIdx.x;
  const int lane = tid & 63;
  const int wv   = tid >> 6;
  const int wm   = wv >> 2;
  const int wn   = wv & 3;
  const int r16  = lane & 15;
  const int quad = lane >> 4;

  // staging precompute. A chunk h = rows {h*64+[0,64)} U {128+h*64+[0,64)} (quadrant-matched);
  // B chunk h = rows h*128+[0,128).
  const unsigned short* gAp[2][2];
  const unsigned short* gBp[2][2];
  int lAo[2][2], lBo[2][2];
#pragma unroll
  for (int h = 0; h < 2; ++h)
#pragma unroll
    for (int jj = 0; jj < 2; ++jj) {
      const int id = jj * 512 + tid;
      const int rp = id >> 3, cc = id & 7;
      const int rowA = h * 64 + ((rp & 64) << 1) + (rp & 63);
      const int tok  = perm[eoff + min(rowA, valid - 1)];
      gAp[h][jj] = xbf + (size_t)tok * HD + ((cc ^ (rowA & 7)) << 3);
      lAo[h][jj] = rowA * 64 + cc * 8;
      const int rowB = h * 128 + rp;
      const int brow = (nn == 0) ? (((h == 0) ? ef : es) * 128 + rp)
                                 : 1024 + (nn - 1) * 256 + rowB;
      gBp[h][jj] = W1cat + (size_t)brow * HD + ((cc ^ (rowB & 7)) << 3);
      lBo[h][jj] = rowB * 64 + cc * 8;
    }

  unsigned short* AsB = As;
  unsigned short* BsB = Bs;

  const int swz = (quad ^ (r16 & 7)) << 3;
  const int a0 = (wm * 128 + r16) * 64 + swz;
  const int b0 = (wn * 64 + r16) * 64 + swz;

  f32x4 acc[8][4];
#pragma unroll
  for (int i = 0; i < 8; ++i)
#pragma unroll
    for (int j = 0; j < 4; ++j) acc[i][j] = (f32x4){0.f, 0.f, 0.f, 0.f};
  bf16x8 av[4][2], bv[2][2];

#define STG_A1K(t, h) do { const int b_ = (((t) & 1) << 14); const int o_ = ((t) << 6); \
    gl2lds16(gAp[h][0] + o_, AsB + b_ + lAo[h][0]);                                     \
    gl2lds16(gAp[h][1] + o_, AsB + b_ + lAo[h][1]); } while (0)
#define STG_B1K(t, h) do { const int b_ = (((t) & 1) << 14); const int o_ = ((t) << 6); \
    gl2lds16(gBp[h][0] + o_, BsB + b_ + lBo[h][0]);                                     \
    gl2lds16(gBp[h][1] + o_, BsB + b_ + lBo[h][1]); } while (0)

  // prologue: A(0), B(0), A(1)  [12 loads]; wait tile0 landed (A(1)'s 4 still flying)
  STG_A1K(0, 0); STG_A1K(0, 1);
  STG_B1K(0, 0); STG_B1K(0, 1);
  STG_A1K(1, 0); STG_A1K(1, 1);
  asm volatile("s_waitcnt vmcnt(4)" ::: "memory");
  barx();

#define FC1_ITER(it, LASTF) do {                                                   \
    const int O1 = 2 * (it) + 1, E2 = 2 * (it) + 2, O2 = 2 * (it) + 3;             \
    PH(0, 0, STG_B1K(O1, 0), (void)0);                                             \
    PH(1, 0, STG_B1K(O1, 1), (void)0);                                             \
    PH(2, 0, { if (!(LASTF)) STG_A1K(E2, 0); }, (void)0);                          \
    PH(3, 0, { if (!(LASTF)) STG_A1K(E2, 1); },                                    \
        { if (LASTF) asm volatile("s_waitcnt vmcnt(0)" ::: "memory");              \
          else       asm volatile("s_waitcnt vmcnt(4)" ::: "memory"); });          \
    PH(0, 1, { if (!(LASTF)) STG_B1K(E2, 0); }, (void)0);                          \
    PH(1, 1, { if (!(LASTF)) STG_B1K(E2, 1); }, (void)0);                          \
    PH(2, 1, { if (!(LASTF)) STG_A1K(O2, 0); }, (void)0);                          \
    PH(3, 1, { if (!(LASTF)) STG_A1K(O2, 1); },                                    \
        { if (LASTF) asm volatile("s_waitcnt vmcnt(0)" ::: "memory");              \
          else       asm volatile("s_waitcnt vmcnt(4)" ::: "memory"); });          \
  } while (0)

#pragma unroll 1
  for (int it = 0; it < 7; ++it) FC1_ITER(it, 0);
  FC1_ITER(7, 1);

  // epilogue: relu(acc+b)*scale -> Hbuf
  __syncthreads();
  float2* wl = (float2*)As;
  if (tid < 256) {
    const int tokc = perm[eoff + min(tid, valid - 1)];
    wl[tid] = wpair[tokc];
  }
  __syncthreads();
  float bz[4];
  const int colb = wn * 64 + r16;
#pragma unroll
  for (int n2 = 0; n2 < 4; ++n2) {
    const int col = colb + n2 * 16;
    const int bidx = (nn == 0) ? ((col < 128) ? ef * 128 + col : es * 128 + (col - 128))
                               : 1024 + (nn - 1) * 256 + col;
    bz[n2] = bias1[bidx];
  }
#pragma unroll
  for (int m2 = 0; m2 < 8; ++m2) {
#pragma unroll
    for (int r = 0; r < 4; ++r) {
      const int lrow = wm * 128 + m2 * 16 + quad * 4 + r;
      const float2 w = wl[lrow];
      const float sc = (nn == 0) ? ((wn < 2) ? w.x : w.y) : 1.0f;
      unsigned short* hp = Hbuf + (size_t)(hbase + lrow) * NH + nn * 256 + colb;
#pragma unroll
      for (int n2 = 0; n2 < 4; ++n2) {
        const float v = fmaxf(acc[m2][n2][r] + bz[n2], 0.f) * sc;
        hp[n2 * 16] = f2bf(v);
      }
    }
  }
#undef FC1_ITER
#undef STG_A1K
#undef STG_B1K
}

__device__ __forceinline__ int koB2(int t, int ef, int es) {
  return (t < 2) ? ef * 128 + (t << 6)
       : (t < 4) ? es * 128 + ((t - 2) << 6)
                 : 1024 + ((t - 4) << 6);
}

// ---------------- G2: grouped fc2, 256x256 tile, K=768, 8-phase pipeline ----------------
__global__ __launch_bounds__(512, 2) void moe_fc2(
    const unsigned short* __restrict__ Hbuf, const unsigned short* __restrict__ W2cat,
    const int* __restrict__ perm, const float2* __restrict__ wpair,
    const float* __restrict__ b2, const float* __restrict__ bs2,
    const int4* __restrict__ tiletab, const int* __restrict__ ntct,
    float* __restrict__ out) {
  const int L   = blockIdx.x;
  const int xcd = L & 7;
  const int s   = L >> 3;
  const int mg  = s >> 2;
  const int nn  = s & 3;
  const int mt  = xcd + (mg << 3);
  if (mt >= ntct[0]) return;
  const int4 tt = tiletab[mt];
  const int eoff = tt.y, valid = tt.z, hbase = tt.w;
  int ef = 0, rem = tt.x;
  while (rem >= 7 - ef) { rem -= 7 - ef; ef++; }
  const int es = ef + 1 + rem;
  const int tileN = nn << 8;

  __shared__ __align__(16) unsigned short As[2 * 16384];
  __shared__ __align__(16) unsigned short Bs[2 * 16384];

  const int tid  = threadIdx.x;
  const int lane = tid & 63;
  const int wv   = tid >> 6;
  const int wm   = wv >> 2;
  const int wn   = wv & 3;
  const int r16  = lane & 15;
  const int quad = lane >> 4;

  const unsigned short* gAp[2][2];
  const unsigned short* gBp[2][2];
  int lAo[2][2], lBo[2][2];
#pragma unroll
  for (int h = 0; h < 2; ++h)
#pragma unroll
    for (int jj = 0; jj < 2; ++jj) {
      const int id = jj * 512 + tid;
      const int rp = id >> 3, cc = id & 7;
      const int rowA = h * 64 + ((rp & 64) << 1) + (rp & 63);
      gAp[h][jj] = Hbuf + (size_t)(hbase + rowA) * NH + ((cc ^ (rowA & 7)) << 3);
      lAo[h][jj] = rowA * 64 + cc * 8;
      const int rowB = h * 128 + rp;
      gBp[h][jj] = W2cat + (size_t)(tileN + rowB) * KC2 + ((cc ^ (rowB & 7)) << 3);
      lBo[h][jj] = rowB * 64 + cc * 8;
    }

  unsigned short* AsB = As;
  unsigned short* BsB = Bs;

  const int swz = (quad ^ (r16 & 7)) << 3;
  const int a0 = (wm * 128 + r16) * 64 + swz;
  const int b0 = (wn * 64 + r16) * 64 + swz;

  f32x4 acc[8][4];
#pragma unroll
  for (int i = 0; i < 8; ++i)
#pragma unroll
    for (int j = 0; j < 4; ++j) acc[i][j] = (f32x4){0.f, 0.f, 0.f, 0.f};
  bf16x8 av[4][2], bv[2][2];

#define STG_A2K(t, h) do { const int b_ = (((t) & 1) << 14); const int o_ = ((t) << 6); \
    gl2lds16(gAp[h][0] + o_, AsB + b_ + lAo[h][0]);                                     \
    gl2lds16(gAp[h][1] + o_, AsB + b_ + lAo[h][1]); } while (0)
#define STG_B2K(t, h) do { const int b_ = (((t) & 1) << 14); const int o_ = koB2((t), ef, es); \
    gl2lds16(gBp[h][0] + o_, BsB + b_ + lBo[h][0]);                                     \
    gl2lds16(gBp[h][1] + o_, BsB + b_ + lBo[h][1]); } while (0)

  STG_A2K(0, 0); STG_A2K(0, 1);
  STG_B2K(0, 0); STG_B2K(0, 1);
  STG_A2K(1, 0); STG_A2K(1, 1);
  asm volatile("s_waitcnt vmcnt(4)" ::: "memory");
  barx();

#define FC2_ITER(it, LASTF) do {                                                   \
    const int O1 = 2 * (it) + 1, E2 = 2 * (it) + 2, O2 = 2 * (it) + 3;             \
    PH(0, 0, STG_B2K(O1, 0), (void)0);                                             \
    PH(1, 0, STG_B2K(O1, 1), (void)0);                                             \
    PH(2, 0, { if (!(LASTF)) STG_A2K(E2, 0); }, (void)0);                          \
    PH(3, 0, { if (!(LASTF)) STG_A2K(E2, 1); },                                    \
        { if (LASTF) asm volatile("s_waitcnt vmcnt(0)" ::: "memory");              \
          else       asm volatile("s_waitcnt vmcnt(4)" ::: "memory"); });          \
    PH(0, 1, { if (!(LASTF)) STG_B2K(E2, 0); }, (void)0);                          \
    PH(1, 1, { if (!(LASTF)) STG_B2K(E2, 1); }, (void)0);                          \
    PH(2, 1, { if (!(LASTF)) STG_A2K(O2, 0); }, (void)0);                          \
    PH(3, 1, { if (!(LASTF)) STG_A2K(O2, 1); },                                    \
        { if (LASTF) asm volatile("s_waitcnt vmcnt(0)" ::: "memory");              \
          else       asm volatile("s_waitcnt vmcnt(4)" ::: "memory"); });          \
  } while (0)

#pragma unroll 1
  for (int it = 0; it < 5; ++it) FC2_ITER(it, 0);
  FC2_ITER(5, 1);

  // epilogue: + bs2 + w1*b2[e1] + w2*b2[e2], scatter to out[token]
  __syncthreads();
  float2* wl2 = (float2*)As;
  int* tokl   = (int*)Bs;
  if (tid < 256) {
    const int tokc = perm[eoff + min(tid, valid - 1)];
    tokl[tid] = (tid < valid) ? tokc : -1;
    wl2[tid] = wpair[tokc];
  }
  __syncthreads();
  float bsc[4], b2a[4], b2b[4];
  const int colb = tileN + wn * 64 + r16;
#pragma unroll
  for (int n2 = 0; n2 < 4; ++n2) {
    const int col = colb + n2 * 16;
    bsc[n2] = bs2[col];
    b2a[n2] = b2[(size_t)ef * HD + col];
    b2b[n2] = b2[(size_t)es * HD + col];
  }
#pragma unroll
  for (int m2 = 0; m2 < 8; ++m2) {
#pragma unroll
    for (int r = 0; r < 4; ++r) {
      const int lrow = wm * 128 + m2 * 16 + quad * 4 + r;
      const int tok = tokl[lrow];
      if (tok < 0) continue;
      const float2 w = wl2[lrow];
      float* op = out + (size_t)tok * HD + colb;
#pragma unroll
      for (int n2 = 0; n2 < 4; ++n2)
        op[n2 * 16] = acc[m2][n2][r] + bsc[n2] + w.x * b2a[n2] + w.y * b2b[n2];
    }
  }
#undef FC2_ITER
#undef STG_A2K
#undef STG_B2K
}

extern "C" void kernel_launch(void* const* d_in, const int* in_sizes, int n_in,
                              void* d_out, int out_size, void* d_ws, size_t ws_size,
                              hipStream_t stream) {
  const float* x   = (const float*)d_in[0];
  const float* Wg  = (const float*)d_in[1];
  const float* W1  = (const float*)d_in[2];
  const float* b1  = (const float*)d_in[3];
  const float* W2  = (const float*)d_in[4];
  const float* b2  = (const float*)d_in[5];
  const float* Ws1 = (const float*)d_in[6];
  const float* bs1 = (const float*)d_in[7];
  const float* Ws2 = (const float*)d_in[8];
  const float* bs2 = (const float*)d_in[9];

  char* ws = (char*)d_ws;
  size_t off = 0;
  unsigned short* xbf   = (unsigned short*)(ws + off); off += (size_t)TTOK * HD * 2;        // 32 MiB
  unsigned short* Hbuf  = (unsigned short*)(ws + off); off += (size_t)MAXT * 256 * NH * 2;  // 36 MiB
  unsigned short* W1cat = (unsigned short*)(ws + off); off += (size_t)NC1 * HD * 2;
  unsigned short* W2cat = (unsigned short*)(ws + off); off += (size_t)HD * KC2 * 2;
  float* bias1          = (float*)(ws + off);          off += (size_t)NC1 * 4;
  float2* wpair         = (float2*)(ws + off);         off += (size_t)TTOK * 8;
  int* pid              = (int*)(ws + off);            off += (size_t)TTOK * 4;
  int* perm             = (int*)(ws + off);            off += (size_t)TTOK * 4;
  int4* tiletab         = (int4*)(ws + off);           off += (size_t)MAXT * 16;
  int* ntct             = (int*)(ws + off);            off += 16;

  prep_gate<<<PREPB + GATEB, 256, 0, stream>>>(x, Wg, W1, Ws1, W2, Ws2, b1, bs1,
                                               W1cat, W2cat, bias1, xbf, wpair, pid);
  route_scan<<<NPAIR, 256, 0, stream>>>(pid, perm, tiletab, ntct);
  moe_fc1<<<8 * 12 * 3, 512, 0, stream>>>(xbf, W1cat, perm, wpair, bias1, tiletab, ntct, Hbuf);
  moe_fc2<<<8 * 12 * 4, 512, 0, stream>>>(Hbuf, W2cat, perm, wpair, b2, bs2, tiletab, ntct,
                                          (float*)d_out);
}

// Round 3
// 279.670 us; speedup vs baseline: 1.0537x; 1.0537x over previous
//
#include <hip/hip_runtime.h>
#include <cstdint>

#define TTOK 16384
#define HD   1024
#define NE   8
#define NDE  128
#define NDS  512
#define NC1  1536   // concat fc1 rows: E*DE routed + DS shared
#define KC2  1536   // concat fc2 cols in W2cat
#define NPAIR 28
#define MAXT  96    // max 256-row M-tiles over pair segments
#define PREPB 3080
#define GATEB 1024  // 16 tokens per block
#define NH    768   // grouped hidden: 128(e1)+128(e2)+512(shared)

typedef float  f32x4  __attribute__((ext_vector_type(4)));
typedef __bf16 bf16x8 __attribute__((ext_vector_type(8)));

__device__ __forceinline__ unsigned short f2bf(float f) {
  unsigned int u = __float_as_uint(f);
  u += 0x7fffu + ((u >> 16) & 1u);   // RNE; inputs finite
  return (unsigned short)(u >> 16);
}

__device__ __forceinline__ void gl2lds16(const void* gp, void* lp) {
  void* g0 = const_cast<void*>(gp);
  __builtin_amdgcn_global_load_lds((__attribute__((address_space(1))) void*)g0,
                                   (__attribute__((address_space(3))) void*)lp,
                                   16, 0, 0);
}

__device__ __forceinline__ void barx() {
  asm volatile("" ::: "memory");
  __builtin_amdgcn_s_barrier();
  asm volatile("" ::: "memory");
}

// ---- 8-phase GEMM phase helpers (256x256 tile, BK=64, 8 waves, wave tile 128x64) ----
// Quadrant Q: MH = Q>>1 picks mi 0-3 / 4-7 (A half), NHF = Q&1 picks ni 0-1 / 2-3 (B half).
template<int Q>
__device__ __forceinline__ void phase_reads(const unsigned short* Ab, const unsigned short* Bb,
                                            int bs, int a0, int b0,
                                            bf16x8 (&av)[4][2], bf16x8 (&bv)[2][2]) {
  constexpr int MH = Q >> 1, NHF = Q & 1;
  if constexpr (NHF == 0) {
#pragma unroll
    for (int m = 0; m < 4; ++m) {
      const int ao = a0 + (MH * 4 + m) * 1024;
      av[m][0] = *(const bf16x8*)(Ab + bs + ao);
      av[m][1] = *(const bf16x8*)(Ab + bs + (ao ^ 32));
    }
  }
#pragma unroll
  for (int n = 0; n < 2; ++n) {
    const int bo = b0 + (NHF * 2 + n) * 1024;
    bv[n][0] = *(const bf16x8*)(Bb + bs + bo);
    bv[n][1] = *(const bf16x8*)(Bb + bs + (bo ^ 32));
  }
}

template<int Q>
__device__ __forceinline__ void phase_mfma2(bf16x8 (&av)[4][2], bf16x8 (&bv)[2][2],
                                            f32x4 (&acc)[8][4]) {
  constexpr int MH = Q >> 1, NHF = Q & 1;
  __builtin_amdgcn_s_setprio(1);
#pragma unroll
  for (int ks = 0; ks < 2; ++ks)
#pragma unroll
    for (int m = 0; m < 4; ++m)
#pragma unroll
      for (int n = 0; n < 2; ++n)
        acc[MH * 4 + m][NHF * 2 + n] = __builtin_amdgcn_mfma_f32_16x16x32_bf16(
            av[m][ks], bv[n][ks], acc[MH * 4 + m][NHF * 2 + n], 0, 0, 0);
  __builtin_amdgcn_s_setprio(0);
}

// Phase: ds_read quadrant || issue stage units -> [vm wait] -> [lgkm pace] -> barrier ->
//        lgkm(0) -> MFMA -> barrier.   (no sched_barrier: let compiler schedule)
#define PH(Q, BH, STG, VMW, PRELG) do {                             \
    phase_reads<Q>(AsB, BsB, (BH) * 16384, a0, b0, av, bv);         \
    STG;                                                            \
    VMW;                                                            \
    PRELG;                                                          \
    barx();                                                         \
    asm volatile("s_waitcnt lgkmcnt(0)" ::: "memory");              \
    phase_mfma2<Q>(av, bv, acc);                                    \
    barx();                                                         \
  } while (0)

#define LG8  asm volatile("s_waitcnt lgkmcnt(8)" ::: "memory")
#define VM2  asm volatile("s_waitcnt vmcnt(2)" ::: "memory")
#define VM0  asm volatile("s_waitcnt vmcnt(0)" ::: "memory")

// ---------------- K1: fused weight prep + gate (unchanged) ----------------
__global__ __launch_bounds__(256) void prep_gate(
    const float* __restrict__ x, const float* __restrict__ Wg,
    const float* __restrict__ W1, const float* __restrict__ Ws1,
    const float* __restrict__ W2, const float* __restrict__ Ws2,
    const float* __restrict__ b1, const float* __restrict__ bs1,
    unsigned short* __restrict__ W1cat, unsigned short* __restrict__ W2cat,
    float* __restrict__ bias1, unsigned short* __restrict__ xbf,
    float2* __restrict__ wpair, int* __restrict__ pid) {
  if (blockIdx.x < PREPB) {
    const int total = NC1 * HD + HD * KC2 + NC1;
    for (int idx = blockIdx.x * 256 + threadIdx.x; idx < total; idx += PREPB * 256) {
      if (idx < NC1 * HD) {
        int r = idx >> 10, k = idx & 1023;
        float v = (r < 1024) ? W1[idx] : Ws1[(size_t)(r - 1024) * HD + k];
        W1cat[idx] = f2bf(v);
      } else if (idx < NC1 * HD + HD * KC2) {
        int i2 = idx - NC1 * HD;
        int h = i2 / KC2;
        int j = i2 - h * KC2;
        float v = (j < 1024) ? W2[(size_t)((j >> 7) * HD + h) * NDE + (j & 127)]
                             : Ws2[(size_t)h * NDS + (j - 1024)];
        W2cat[i2] = f2bf(v);
      } else {
        int r = idx - (NC1 * HD + HD * KC2);
        bias1[r] = (r < 1024) ? b1[r] : bs1[r - 1024];
      }
    }
    return;
  }
  // ---- gate: block handles 16 tokens ----
  __shared__ float part[16 * 8 * 64];
  __shared__ float lgs[128];

  const int tid  = threadIdx.x;
  const int lane = tid & 63;
  const int wv   = tid >> 6;
  const int g    = blockIdx.x - PREPB;
  const int tokb = g * 16 + wv * 4;

  const float* xr = x + (size_t)tokb * HD + lane * 16;
  float4 xv[4][4];
#pragma unroll
  for (int t = 0; t < 4; ++t)
#pragma unroll
    for (int c = 0; c < 4; ++c)
      xv[t][c] = ((const float4*)(xr + (size_t)t * HD))[c];

#pragma unroll
  for (int t = 0; t < 4; ++t) {
    unsigned short* xo = xbf + (size_t)(tokb + t) * HD + lane * 16;
    union { unsigned short us[8]; uint4 v; } pk;
    pk.us[0] = f2bf(xv[t][0].x); pk.us[1] = f2bf(xv[t][0].y);
    pk.us[2] = f2bf(xv[t][0].z); pk.us[3] = f2bf(xv[t][0].w);
    pk.us[4] = f2bf(xv[t][1].x); pk.us[5] = f2bf(xv[t][1].y);
    pk.us[6] = f2bf(xv[t][1].z); pk.us[7] = f2bf(xv[t][1].w);
    ((uint4*)xo)[0] = pk.v;
    pk.us[0] = f2bf(xv[t][2].x); pk.us[1] = f2bf(xv[t][2].y);
    pk.us[2] = f2bf(xv[t][2].z); pk.us[3] = f2bf(xv[t][2].w);
    pk.us[4] = f2bf(xv[t][3].x); pk.us[5] = f2bf(xv[t][3].y);
    pk.us[6] = f2bf(xv[t][3].z); pk.us[7] = f2bf(xv[t][3].w);
    ((uint4*)xo)[1] = pk.v;
  }

  float p[4][8];
#pragma unroll
  for (int t = 0; t < 4; ++t)
#pragma unroll
    for (int e = 0; e < 8; ++e) p[t][e] = 0.f;
#pragma unroll
  for (int e = 0; e < 8; ++e) {
    const float4* wr = (const float4*)(Wg + (size_t)e * HD + lane * 16);
    float4 w0 = wr[0], w1 = wr[1], w2 = wr[2], w3 = wr[3];
#pragma unroll
    for (int t = 0; t < 4; ++t) {
      p[t][e] = w0.x * xv[t][0].x + w0.y * xv[t][0].y + w0.z * xv[t][0].z + w0.w * xv[t][0].w +
                w1.x * xv[t][1].x + w1.y * xv[t][1].y + w1.z * xv[t][1].z + w1.w * xv[t][1].w +
                w2.x * xv[t][2].x + w2.y * xv[t][2].y + w2.z * xv[t][2].z + w2.w * xv[t][2].w +
                w3.x * xv[t][3].x + w3.y * xv[t][3].y + w3.z * xv[t][3].z + w3.w * xv[t][3].w;
    }
  }
#pragma unroll
  for (int t = 0; t < 4; ++t)
#pragma unroll
    for (int e = 0; e < 8; ++e) {
      int j = (wv * 4 + t) * 8 + e;
      part[j * 64 + ((lane + 4 * j) & 63)] = p[t][e];
    }
  __syncthreads();

  if (tid < 128) {
    float s = 0.f;
#pragma unroll
    for (int m = 0; m < 16; ++m) {
      int kk = (4 * m + 4 * tid) & 63;
      float4 v = *(const float4*)&part[tid * 64 + kk];
      s += v.x + v.y + v.z + v.w;
    }
    lgs[tid] = s;
  }
  __syncthreads();

  if (tid < 16) {
    float lg[8];
#pragma unroll
    for (int e = 0; e < 8; ++e) lg[e] = lgs[tid * 8 + e];
    int i1 = 0; float m1 = lg[0];
#pragma unroll
    for (int e = 1; e < 8; ++e) { if (lg[e] > m1) { m1 = lg[e]; i1 = e; } }
    int i2 = -1; float m2 = -3.4e38f;
#pragma unroll
    for (int e = 0; e < 8; ++e) { if (e != i1 && lg[e] > m2) { m2 = lg[e]; i2 = e; } }
    float Z = 0.f;
#pragma unroll
    for (int e = 0; e < 8; ++e) Z += expf(lg[e] - m1);
    float s1 = 1.f / Z;
    float s2 = expf(m2 - m1) / Z;
    float dn = s1 + s2 + 1e-20f;
    float w1 = s1 / dn, w2 = s2 / dn;
    int ef, es; float wf, wsx;
    if (i1 < i2) { ef = i1; es = i2; wf = w1; wsx = w2; }
    else         { ef = i2; es = i1; wf = w2; wsx = w1; }
    int pq = ef * 7 - (ef * (ef - 1)) / 2 + (es - ef - 1);
    int t = g * 16 + tid;
    wpair[t] = make_float2(wf, wsx);
    pid[t] = pq;
  }
}

// ---------------- K2: atomic-free routing (256-row tiles) ----------------
__global__ __launch_bounds__(256) void route_scan(const int* __restrict__ pid,
                                                  int* __restrict__ perm,
                                                  int4* __restrict__ tiletab,
                                                  int* __restrict__ ntct) {
  __shared__ int hist[256 * 29];
  __shared__ int totals[NPAIR];
  __shared__ int spre[256];
  const int p   = blockIdx.x;
  const int tid = threadIdx.x;
#pragma unroll
  for (int q = 0; q < 29; ++q) hist[tid * 29 + q] = 0;
  __syncthreads();
  for (int k = 0; k < 64; ++k) {
    int q = pid[tid + (k << 8)];
    hist[tid * 29 + q]++;
  }
  __syncthreads();
  if (tid < NPAIR) {
    int s = 0;
    for (int i = 0; i < 256; ++i) s += hist[i * 29 + tid];
    totals[tid] = s;
  }
  __syncthreads();
  const int mycnt = hist[tid * 29 + p];
  spre[tid] = mycnt;
  __syncthreads();
  for (int d = 1; d < 256; d <<= 1) {
    int add = (tid >= d) ? spre[tid - d] : 0;
    __syncthreads();
    spre[tid] += add;
    __syncthreads();
  }
  int estart = 0, tstart = 0;
  for (int q = 0; q < p; ++q) { estart += totals[q]; tstart += (totals[q] + 255) >> 8; }
  const int cp = totals[p];
  const int nt = (cp + 255) >> 8;
  if (p == NPAIR - 1 && tid == 0) ntct[0] = tstart + nt;
  for (int k = tid; k < nt; k += 256) {
    int4 e;
    e.x = p;
    e.y = estart + (k << 8);
    e.z = min(256, cp - (k << 8));
    e.w = (tstart + k) << 8;   // hbase in rows
    tiletab[tstart + k] = e;
  }
  int wr = estart + spre[tid] - mycnt;
  for (int k = 0; k < 64; ++k) {
    int t = tid + (k << 8);
    if (pid[t] == p) perm[wr++] = t;
  }
}

// ---------------- G1: grouped fc1, 256x256 tile, legal-window 8-phase pipeline ----------------
__global__ __launch_bounds__(512, 2) void moe_fc1(
    const unsigned short* __restrict__ xbf, const unsigned short* __restrict__ W1cat,
    const int* __restrict__ perm, const float2* __restrict__ wpair,
    const float* __restrict__ bias1, const int4* __restrict__ tiletab,
    const int* __restrict__ ntct, unsigned short* __restrict__ Hbuf) {
  const int L   = blockIdx.x;
  const int xcd = L & 7;
  const int s   = L >> 3;
  const int mg  = s / 3;
  const int nn  = s - mg * 3;       // 0: routed e1|e2, 1: shared[0:256), 2: shared[256:512)
  const int mt  = xcd + (mg << 3);
  if (mt >= ntct[0]) return;
  const int4 tt = tiletab[mt];
  const int eoff = tt.y, valid = tt.z, hbase = tt.w;
  int ef = 0, rem = tt.x;
  while (rem >= 7 - ef) { rem -= 7 - ef; ef++; }
  const int es = ef + 1 + rem;

  __shared__ __align__(16) unsigned short As[2 * 16384];   // 64 KiB (2 bufs x 256x64)
  __shared__ __align__(16) unsigned short Bs[2 * 16384];   // 64 KiB

  const int tid  = threadIdx.x;
  const int lane = tid & 63;
  const int wv   = tid >> 6;
  const int wm   = wv >> 2;
  const int wn   = wv & 3;
  const int r16  = lane & 15;
  const int quad = lane >> 4;

  // staging precompute. A chunk h = rows {h*64+[0,64)} U {128+h*64+[0,64)} (quadrant MH=h);
  // B chunk h = rows h*128+[0,128) (output cols of waves wn in {2h,2h+1}).
  const unsigned short* gAp[2][2];
  const unsigned short* gBp[2][2];
  int lAo[2][2], lBo[2][2];
#pragma unroll
  for (int h = 0; h < 2; ++h)
#pragma unroll
    for (int jj = 0; jj < 2; ++jj) {
      const int id = jj * 512 + tid;
      const int rp = id >> 3, cc = id & 7;
      const int rowA = h * 64 + ((rp & 64) << 1) + (rp & 63);
      const int tok  = perm[eoff + min(rowA, valid - 1)];
      gAp[h][jj] = xbf + (size_t)tok * HD + ((cc ^ (rowA & 7)) << 3);
      lAo[h][jj] = rowA * 64 + cc * 8;
      const int rowB = h * 128 + rp;
      const int brow = (nn == 0) ? (((h == 0) ? ef : es) * 128 + rp)
                                 : 1024 + (nn - 1) * 256 + rowB;
      gBp[h][jj] = W1cat + (size_t)brow * HD + ((cc ^ (rowB & 7)) << 3);
      lBo[h][jj] = rowB * 64 + cc * 8;
    }

  unsigned short* AsB = As;
  unsigned short* BsB = Bs;

  const int swz = (quad ^ (r16 & 7)) << 3;
  const int a0 = (wm * 128 + r16) * 64 + swz;
  const int b0 = (wn * 64 + r16) * 64 + swz;

  f32x4 acc[8][4];
#pragma unroll
  for (int i = 0; i < 8; ++i)
#pragma unroll
    for (int j = 0; j < 4; ++j) acc[i][j] = (f32x4){0.f, 0.f, 0.f, 0.f};
  bf16x8 av[4][2], bv[2][2];

#define STG_A1K(t, h) do { const int b_ = (((t) & 1) << 14); const int o_ = ((t) << 6); \
    gl2lds16(gAp[h][0] + o_, AsB + b_ + lAo[h][0]);                                     \
    gl2lds16(gAp[h][1] + o_, AsB + b_ + lAo[h][1]); } while (0)
#define STG_B1K(t, h) do { const int b_ = (((t) & 1) << 14); const int o_ = ((t) << 6); \
    gl2lds16(gBp[h][0] + o_, BsB + b_ + lBo[h][0]);                                     \
    gl2lds16(gBp[h][1] + o_, BsB + b_ + lBo[h][1]); } while (0)

  // prologue: tile0 full + A(1,h0) (emulating steady-state "prev iter" slots)
  STG_A1K(0, 0); STG_A1K(0, 1);
  STG_B1K(0, 0); STG_B1K(0, 1);
  STG_A1K(1, 0);
  VM2;           // tile 0 landed; A(1,h0) in flight
  barx();

  // Steady iteration reading (T=2it, T+1). Stage units (legal write windows):
  //  ph1: A(T+1,h1), B(T+1,h0)   [overwrites T-1 data, read last iter]
  //  ph2: B(T+1,h1)
  //  ph3: A(T+2,h0)              [overwrites A(T,h0), read ph1-2]
  //  ph4: vmcnt(2)               [T+1 group landed; A(T+2,h0) flying]
  //  ph5: A(T+2,h1), B(T+2,h0)   [overwrite T data read ph3-4 / ph1-4]
  //  ph6: B(T+2,h1)
  //  ph7: A(T+3,h0)              [overwrites A(T+1,h0), read ph5-6]
  //  ph8: vmcnt(2)               [T+2 group landed; A(T+3,h0) flying]
#define FC1_ITER(it, LASTF) do {                                                    \
    const int T1 = 2 * (it) + 1, T2 = 2 * (it) + 2, T3 = 2 * (it) + 3;              \
    PH(0, 0, { STG_A1K(T1, 1); STG_B1K(T1, 0); }, (void)0, LG8);                    \
    PH(1, 0, { STG_B1K(T1, 1); }, (void)0, (void)0);                                \
    PH(2, 0, { if (!(LASTF)) STG_A1K(T2, 0); }, (void)0, LG8);                      \
    PH(3, 0, (void)0, { if (LASTF) { VM0; } else { VM2; } }, (void)0);              \
    PH(0, 1, { if (!(LASTF)) { STG_A1K(T2, 1); STG_B1K(T2, 0); } }, (void)0, LG8);  \
    PH(1, 1, { if (!(LASTF)) STG_B1K(T2, 1); }, (void)0, (void)0);                  \
    PH(2, 1, { if (!(LASTF)) STG_A1K(T3, 0); }, (void)0, LG8);                      \
    PH(3, 1, (void)0, { if (!(LASTF)) { VM2; } }, (void)0);                         \
  } while (0)

#pragma unroll 1
  for (int it = 0; it < 7; ++it) FC1_ITER(it, 0);
  FC1_ITER(7, 1);

  // epilogue: relu(acc+b)*scale -> Hbuf
  __syncthreads();
  float2* wl = (float2*)As;
  if (tid < 256) {
    const int tokc = perm[eoff + min(tid, valid - 1)];
    wl[tid] = wpair[tokc];
  }
  __syncthreads();
  float bz[4];
  const int colb = wn * 64 + r16;
#pragma unroll
  for (int n2 = 0; n2 < 4; ++n2) {
    const int col = colb + n2 * 16;
    const int bidx = (nn == 0) ? ((col < 128) ? ef * 128 + col : es * 128 + (col - 128))
                               : 1024 + (nn - 1) * 256 + col;
    bz[n2] = bias1[bidx];
  }
#pragma unroll
  for (int m2 = 0; m2 < 8; ++m2) {
#pragma unroll
    for (int r = 0; r < 4; ++r) {
      const int lrow = wm * 128 + m2 * 16 + quad * 4 + r;
      const float2 w = wl[lrow];
      const float sc = (nn == 0) ? ((wn < 2) ? w.x : w.y) : 1.0f;
      unsigned short* hp = Hbuf + (size_t)(hbase + lrow) * NH + nn * 256 + colb;
#pragma unroll
      for (int n2 = 0; n2 < 4; ++n2) {
        const float v = fmaxf(acc[m2][n2][r] + bz[n2], 0.f) * sc;
        hp[n2 * 16] = f2bf(v);
      }
    }
  }
#undef FC1_ITER
#undef STG_A1K
#undef STG_B1K
}

// ---------------- G2: grouped fc2 (proven round-0 128x128 body; mh-split of 256 tiles) ----------------
__global__ __launch_bounds__(256) void moe_fc2(const unsigned short* __restrict__ Hbuf,
                                               const unsigned short* __restrict__ W2cat,
                                               const int* __restrict__ perm,
                                               const float2* __restrict__ wpair,
                                               const float* __restrict__ b2,
                                               const float* __restrict__ bs2,
                                               const int4* __restrict__ tiletab,
                                               const int* __restrict__ ntct,
                                               float* __restrict__ out) {
  const int L   = blockIdx.x;
  const int xcd = L & 7;
  const int s   = L >> 3;
  const int mg  = s >> 4;
  const int rm  = s & 15;
  const int mh  = rm >> 3;
  const int nn  = rm & 7;
  const int mt  = xcd + (mg << 3);
  if (mt >= ntct[0]) return;
  const int4 tt = tiletab[mt];
  const int v128 = tt.z - (mh << 7);
  if (v128 <= 0) return;
  const int eoff = tt.y + (mh << 7);
  const int valid = min(128, v128);
  const int hbase = tt.w + (mh << 7);
  int ef = 0, rem = tt.x;
  while (rem >= 7 - ef) { rem -= 7 - ef; ef++; }
  const int es = ef + 1 + rem;
  const int tileN = nn << 7;

  __shared__ __align__(16) unsigned short As[128 * 64];
  __shared__ __align__(16) unsigned short Bs[128 * 64];

  const int tid  = threadIdx.x;
  const int lane = tid & 63;
  const int wv   = tid >> 6;
  const int wm   = wv >> 1;
  const int wn   = wv & 1;
  const int r16  = lane & 15;
  const int quad = lane >> 4;

  const unsigned short* gA[4];
  const unsigned short* gB[4];
  unsigned short* lA[4];
  unsigned short* lB[4];
#pragma unroll
  for (int i = 0; i < 4; ++i) {
    int idx = i * 256 + tid;
    int row = idx >> 3;
    int cc  = idx & 7;
    int kc  = cc ^ (row & 7);
    gA[i] = Hbuf + (size_t)(hbase + row) * NH + kc * 8;
    gB[i] = W2cat + (size_t)(tileN + row) * KC2 + kc * 8;
    lA[i] = As + idx * 8;
    lB[i] = Bs + idx * 8;
  }

  int aoff[4], boff[4];
#pragma unroll
  for (int i = 0; i < 4; ++i) {
    int ra = wm * 64 + i * 16 + r16;
    aoff[i] = ra * 64 + ((quad ^ (ra & 7)) << 3);
    int rb = wn * 64 + i * 16 + r16;
    boff[i] = rb * 64 + ((quad ^ (rb & 7)) << 3);
  }

  f32x4 acc[4][4];
#pragma unroll
  for (int i = 0; i < 4; ++i)
#pragma unroll
    for (int j = 0; j < 4; ++j) acc[i][j] = (f32x4){0.f, 0.f, 0.f, 0.f};

  for (int kt = 0; kt < 12; ++kt) {
    const int koA = kt << 6;
    const int koB = (kt < 2) ? ef * 128 + (kt << 6)
                 : (kt < 4) ? es * 128 + ((kt - 2) << 6)
                            : 1024 + ((kt - 4) << 6);
#pragma unroll
    for (int i = 0; i < 4; ++i) gl2lds16(gA[i] + koA, lA[i]);
#pragma unroll
    for (int i = 0; i < 4; ++i) gl2lds16(gB[i] + koB, lB[i]);
    __syncthreads();
#pragma unroll
    for (int g = 0; g < 2; ++g) {
      const int gx = g << 5;
      bf16x8 av[4], bvv[4];
#pragma unroll
      for (int i = 0; i < 4; ++i) av[i] = *(const bf16x8*)(As + (aoff[i] ^ gx));
#pragma unroll
      for (int j = 0; j < 4; ++j) bvv[j] = *(const bf16x8*)(Bs + (boff[j] ^ gx));
#pragma unroll
      for (int i = 0; i < 4; ++i)
#pragma unroll
        for (int j = 0; j < 4; ++j)
          acc[i][j] = __builtin_amdgcn_mfma_f32_16x16x32_bf16(av[i], bvv[j], acc[i][j], 0, 0, 0);
    }
    __syncthreads();
  }

  // epilogue: + bs2 + w1*b2[e1] + w2*b2[e2], scatter to out[token]
  float2* wl2 = (float2*)As;
  int* tokl   = (int*)Bs;
  if (tid < 128) {
    int tokc = perm[eoff + min(tid, valid - 1)];
    tokl[tid] = (tid < valid) ? tokc : -1;
    wl2[tid] = wpair[tokc];
  }
  __syncthreads();
  float bsc[4], b2a[4], b2b[4];
#pragma unroll
  for (int j = 0; j < 4; ++j) {
    const int col = tileN + wn * 64 + j * 16 + r16;
    bsc[j] = bs2[col];
    b2a[j] = b2[(size_t)ef * HD + col];
    b2b[j] = b2[(size_t)es * HD + col];
  }
#pragma unroll
  for (int i = 0; i < 4; ++i) {
#pragma unroll
    for (int r = 0; r < 4; ++r) {
      const int lrow = wm * 64 + i * 16 + quad * 4 + r;
      const int tok = tokl[lrow];
      if (tok < 0) continue;
      const float2 w = wl2[lrow];
#pragma unroll
      for (int j = 0; j < 4; ++j) {
        const int col = tileN + wn * 64 + j * 16 + r16;
        out[(size_t)tok * HD + col] = acc[i][j][r] + bsc[j] + w.x * b2a[j] + w.y * b2b[j];
      }
    }
  }
}

extern "C" void kernel_launch(void* const* d_in, const int* in_sizes, int n_in,
                              void* d_out, int out_size, void* d_ws, size_t ws_size,
                              hipStream_t stream) {
  const float* x   = (const float*)d_in[0];
  const float* Wg  = (const float*)d_in[1];
  const float* W1  = (const float*)d_in[2];
  const float* b1  = (const float*)d_in[3];
  const float* W2  = (const float*)d_in[4];
  const float* b2  = (const float*)d_in[5];
  const float* Ws1 = (const float*)d_in[6];
  const float* bs1 = (const float*)d_in[7];
  const float* Ws2 = (const float*)d_in[8];
  const float* bs2 = (const float*)d_in[9];

  char* ws = (char*)d_ws;
  size_t off = 0;
  unsigned short* xbf   = (unsigned short*)(ws + off); off += (size_t)TTOK * HD * 2;        // 32 MiB
  unsigned short* Hbuf  = (unsigned short*)(ws + off); off += (size_t)MAXT * 256 * NH * 2;  // 36 MiB
  unsigned short* W1cat = (unsigned short*)(ws + off); off += (size_t)NC1 * HD * 2;
  unsigned short* W2cat = (unsigned short*)(ws + off); off += (size_t)HD * KC2 * 2;
  float* bias1          = (float*)(ws + off);          off += (size_t)NC1 * 4;
  float2* wpair         = (float2*)(ws + off);         off += (size_t)TTOK * 8;
  int* pid              = (int*)(ws + off);            off += (size_t)TTOK * 4;
  int* perm             = (int*)(ws + off);            off += (size_t)TTOK * 4;
  int4* tiletab         = (int4*)(ws + off);           off += (size_t)MAXT * 16;
  int* ntct             = (int*)(ws + off);            off += 16;

  prep_gate<<<PREPB + GATEB, 256, 0, stream>>>(x, Wg, W1, Ws1, W2, Ws2, b1, bs1,
                                               W1cat, W2cat, bias1, xbf, wpair, pid);
  route_scan<<<NPAIR, 256, 0, stream>>>(pid, perm, tiletab, ntct);
  moe_fc1<<<8 * 12 * 3, 512, 0, stream>>>(xbf, W1cat, perm, wpair, bias1, tiletab, ntct, Hbuf);
  moe_fc2<<<8 * 12 * 16, 256, 0, stream>>>(Hbuf, W2cat, perm, wpair, b2, bs2, tiletab, ntct,
                                           (float*)d_out);
}

// Round 5
// 252.982 us; speedup vs baseline: 1.1648x; 1.1055x over previous
//
#include <hip/hip_runtime.h>
#include <cstdint>

#define TTOK 16384
#define HD   1024
#define NE   8
#define NDE  128
#define NDS  512
#define NC1  1536   // concat fc1 rows: E*DE routed + DS shared
#define KC2  1536   // concat fc2 cols in W2cat
#define NPAIR 28
#define MAXT  160   // max M-tiles over pair segments (<=128+27, padded to 8*20)
#define PREPB 3080
#define GATEB 1024  // 16 tokens per block
#define NH    768   // grouped hidden: 128(e1)+128(e2)+512(shared)

typedef float  f32x4  __attribute__((ext_vector_type(4)));
typedef __bf16 bf16x8 __attribute__((ext_vector_type(8)));

__device__ __forceinline__ unsigned short f2bf(float f) {
  unsigned int u = __float_as_uint(f);
  u += 0x7fffu + ((u >> 16) & 1u);   // RNE; inputs finite
  return (unsigned short)(u >> 16);
}

__device__ __forceinline__ void gl2lds16(const void* gp, void* lp) {
  void* g0 = const_cast<void*>(gp);
  __builtin_amdgcn_global_load_lds((__attribute__((address_space(1))) void*)g0,
                                   (__attribute__((address_space(3))) void*)lp,
                                   16, 0, 0);
}

__device__ __forceinline__ void barx() {
  asm volatile("" ::: "memory");
  __builtin_amdgcn_s_barrier();
  asm volatile("" ::: "memory");
}
#define VM8  asm volatile("s_waitcnt vmcnt(8)" ::: "memory")
#define VM0  asm volatile("s_waitcnt vmcnt(0)" ::: "memory")

// ---------------- K1: fused weight prep + gate ----------------
__global__ __launch_bounds__(256) void prep_gate(
    const float* __restrict__ x, const float* __restrict__ Wg,
    const float* __restrict__ W1, const float* __restrict__ Ws1,
    const float* __restrict__ W2, const float* __restrict__ Ws2,
    const float* __restrict__ b1, const float* __restrict__ bs1,
    unsigned short* __restrict__ W1cat, unsigned short* __restrict__ W2cat,
    float* __restrict__ bias1, unsigned short* __restrict__ xbf,
    float2* __restrict__ wpair, int* __restrict__ pid) {
  if (blockIdx.x < PREPB) {
    const int total = NC1 * HD + HD * KC2 + NC1;
    for (int idx = blockIdx.x * 256 + threadIdx.x; idx < total; idx += PREPB * 256) {
      if (idx < NC1 * HD) {
        int r = idx >> 10, k = idx & 1023;
        float v = (r < 1024) ? W1[idx] : Ws1[(size_t)(r - 1024) * HD + k];
        W1cat[idx] = f2bf(v);
      } else if (idx < NC1 * HD + HD * KC2) {
        int i2 = idx - NC1 * HD;
        int h = i2 / KC2;
        int j = i2 - h * KC2;
        float v = (j < 1024) ? W2[(size_t)((j >> 7) * HD + h) * NDE + (j & 127)]
                             : Ws2[(size_t)h * NDS + (j - 1024)];
        W2cat[i2] = f2bf(v);
      } else {
        int r = idx - (NC1 * HD + HD * KC2);
        bias1[r] = (r < 1024) ? b1[r] : bs1[r - 1024];
      }
    }
    return;
  }
  // ---- gate: block handles 16 tokens ----
  __shared__ float part[16 * 8 * 64];   // 32 KB: [job=(tok*8+e)][lane] rotated
  __shared__ float lgs[128];

  const int tid  = threadIdx.x;
  const int lane = tid & 63;
  const int wv   = tid >> 6;
  const int g    = blockIdx.x - PREPB;
  const int tokb = g * 16 + wv * 4;

  // batched loads: 4 tokens x 4 float4 (16 outstanding)
  const float* xr = x + (size_t)tokb * HD + lane * 16;
  float4 xv[4][4];
#pragma unroll
  for (int t = 0; t < 4; ++t)
#pragma unroll
    for (int c = 0; c < 4; ++c)
      xv[t][c] = ((const float4*)(xr + (size_t)t * HD))[c];

  // xbf stores (2 uint4 per token per lane)
#pragma unroll
  for (int t = 0; t < 4; ++t) {
    unsigned short* xo = xbf + (size_t)(tokb + t) * HD + lane * 16;
    union { unsigned short us[8]; uint4 v; } pk;
    pk.us[0] = f2bf(xv[t][0].x); pk.us[1] = f2bf(xv[t][0].y);
    pk.us[2] = f2bf(xv[t][0].z); pk.us[3] = f2bf(xv[t][0].w);
    pk.us[4] = f2bf(xv[t][1].x); pk.us[5] = f2bf(xv[t][1].y);
    pk.us[6] = f2bf(xv[t][1].z); pk.us[7] = f2bf(xv[t][1].w);
    ((uint4*)xo)[0] = pk.v;
    pk.us[0] = f2bf(xv[t][2].x); pk.us[1] = f2bf(xv[t][2].y);
    pk.us[2] = f2bf(xv[t][2].z); pk.us[3] = f2bf(xv[t][2].w);
    pk.us[4] = f2bf(xv[t][3].x); pk.us[5] = f2bf(xv[t][3].y);
    pk.us[6] = f2bf(xv[t][3].z); pk.us[7] = f2bf(xv[t][3].w);
    ((uint4*)xo)[1] = pk.v;
  }

  // dots: e outer (Wg loaded once per e, reused for 4 tokens)
  float p[4][8];
#pragma unroll
  for (int t = 0; t < 4; ++t)
#pragma unroll
    for (int e = 0; e < 8; ++e) p[t][e] = 0.f;
#pragma unroll
  for (int e = 0; e < 8; ++e) {
    const float4* wr = (const float4*)(Wg + (size_t)e * HD + lane * 16);
    float4 w0 = wr[0], w1 = wr[1], w2 = wr[2], w3 = wr[3];
#pragma unroll
    for (int t = 0; t < 4; ++t) {
      p[t][e] = w0.x * xv[t][0].x + w0.y * xv[t][0].y + w0.z * xv[t][0].z + w0.w * xv[t][0].w +
                w1.x * xv[t][1].x + w1.y * xv[t][1].y + w1.z * xv[t][1].z + w1.w * xv[t][1].w +
                w2.x * xv[t][2].x + w2.y * xv[t][2].y + w2.z * xv[t][2].z + w2.w * xv[t][2].w +
                w3.x * xv[t][3].x + w3.y * xv[t][3].y + w3.z * xv[t][3].z + w3.w * xv[t][3].w;
    }
  }
  // spill partials to LDS, rotation-swizzled so reduce reads are bank-spread
#pragma unroll
  for (int t = 0; t < 4; ++t)
#pragma unroll
    for (int e = 0; e < 8; ++e) {
      int j = (wv * 4 + t) * 8 + e;
      part[j * 64 + ((lane + 4 * j) & 63)] = p[t][e];
    }
  __syncthreads();

  // reduce: 128 jobs (16 tok x 8 e), each sums 64 partials via 16 b128 reads
  if (tid < 128) {
    float s = 0.f;
#pragma unroll
    for (int m = 0; m < 16; ++m) {
      int kk = (4 * m + 4 * tid) & 63;
      float4 v = *(const float4*)&part[tid * 64 + kk];
      s += v.x + v.y + v.z + v.w;
    }
    lgs[tid] = s;
  }
  __syncthreads();

  // softmax + top2, one thread per token
  if (tid < 16) {
    float lg[8];
#pragma unroll
    for (int e = 0; e < 8; ++e) lg[e] = lgs[tid * 8 + e];
    int i1 = 0; float m1 = lg[0];
#pragma unroll
    for (int e = 1; e < 8; ++e) { if (lg[e] > m1) { m1 = lg[e]; i1 = e; } }
    int i2 = -1; float m2 = -3.4e38f;
#pragma unroll
    for (int e = 0; e < 8; ++e) { if (e != i1 && lg[e] > m2) { m2 = lg[e]; i2 = e; } }
    float Z = 0.f;
#pragma unroll
    for (int e = 0; e < 8; ++e) Z += expf(lg[e] - m1);
    float s1 = 1.f / Z;
    float s2 = expf(m2 - m1) / Z;
    float dn = s1 + s2 + 1e-20f;
    float w1 = s1 / dn, w2 = s2 / dn;
    int ef, es; float wf, wsx;
    if (i1 < i2) { ef = i1; es = i2; wf = w1; wsx = w2; }
    else         { ef = i2; es = i1; wf = w2; wsx = w1; }
    int pq = ef * 7 - (ef * (ef - 1)) / 2 + (es - ef - 1);   // C(8,2) index, ef<es
    int t = g * 16 + tid;
    wpair[t] = make_float2(wf, wsx);
    pid[t] = pq;
  }
}

// ---------------- K2: atomic-free routing: histogram + prefix + rank assignment ----------------
__global__ __launch_bounds__(256) void route_scan(const int* __restrict__ pid,
                                                  int* __restrict__ perm,
                                                  int4* __restrict__ tiletab,
                                                  int* __restrict__ ntct) {
  __shared__ int hist[256 * 29];
  __shared__ int totals[NPAIR];
  __shared__ int spre[256];
  const int p   = blockIdx.x;
  const int tid = threadIdx.x;
#pragma unroll
  for (int q = 0; q < 29; ++q) hist[tid * 29 + q] = 0;
  __syncthreads();
  for (int k = 0; k < 64; ++k) {
    int q = pid[tid + (k << 8)];
    hist[tid * 29 + q]++;
  }
  __syncthreads();
  if (tid < NPAIR) {
    int s = 0;
    for (int i = 0; i < 256; ++i) s += hist[i * 29 + tid];
    totals[tid] = s;
  }
  __syncthreads();
  const int mycnt = hist[tid * 29 + p];
  spre[tid] = mycnt;
  __syncthreads();
  for (int d = 1; d < 256; d <<= 1) {
    int add = (tid >= d) ? spre[tid - d] : 0;
    __syncthreads();
    spre[tid] += add;
    __syncthreads();
  }
  int estart = 0, tstart = 0;
  for (int q = 0; q < p; ++q) { estart += totals[q]; tstart += (totals[q] + 127) >> 7; }
  const int cp = totals[p];
  const int nt = (cp + 127) >> 7;
  if (p == NPAIR - 1 && tid == 0) ntct[0] = tstart + nt;
  for (int k = tid; k < nt; k += 256) {
    int4 e;
    e.x = p;
    e.y = estart + (k << 7);
    e.z = min(128, cp - (k << 7));
    e.w = (tstart + k) << 7;
    tiletab[tstart + k] = e;
  }
  int wr = estart + spre[tid] - mycnt;
  for (int k = 0; k < 64; ++k) {
    int t = tid + (k << 8);
    if (pid[t] == p) perm[wr++] = t;
  }
}

// ---------------- G1: grouped fc1: gather x rows, [128x768] per pair-tile ----------------
// 2-deep prefetch: STAGE(kt+1) issued BEFORE compute(kt); counted vmcnt(8); raw barriers.
__global__ __launch_bounds__(256) void moe_fc1(const unsigned short* __restrict__ xbf,
                                               const unsigned short* __restrict__ W1cat,
                                               const int* __restrict__ perm,
                                               const float2* __restrict__ wpair,
                                               const float* __restrict__ bias1,
                                               const int4* __restrict__ tiletab,
                                               const int* __restrict__ ntct,
                                               unsigned short* __restrict__ Hbuf) {
  const int L   = blockIdx.x;
  const int xcd = L & 7;
  const int s   = L >> 3;
  const int mg  = s / 6;
  const int nn  = s - mg * 6;
  const int mt  = xcd + (mg << 3);
  if (mt >= ntct[0]) return;
  const int4 tt = tiletab[mt];
  const int eoff = tt.y, valid = tt.z, hbase = tt.w;
  int ef = 0, rem = tt.x;
  while (rem >= 7 - ef) { rem -= 7 - ef; ef++; }
  const int es = ef + 1 + rem;
  const int brow = (nn == 0) ? ef * 128 : (nn == 1) ? es * 128 : 1024 + ((nn - 2) << 7);

  __shared__ __align__(16) unsigned short As[2 * 128 * 64];   // 32 KiB (2 bufs)
  __shared__ __align__(16) unsigned short Bs[2 * 128 * 64];   // 32 KiB

  const int tid  = threadIdx.x;
  const int lane = tid & 63;
  const int wv   = tid >> 6;
  const int wm   = wv >> 1;
  const int wn   = wv & 1;
  const int r16  = lane & 15;
  const int quad = lane >> 4;

  const unsigned short* gA[4];
  const unsigned short* gB[4];
  unsigned short* lA[4];
  unsigned short* lB[4];
#pragma unroll
  for (int i = 0; i < 4; ++i) {
    int idx = i * 256 + tid;
    int row = idx >> 3;
    int cc  = idx & 7;
    int kc  = cc ^ (row & 7);
    int tok = perm[eoff + min(row, valid - 1)];
    gA[i] = xbf + (size_t)tok * HD + kc * 8;
    gB[i] = W1cat + (size_t)(brow + row) * HD + kc * 8;
    lA[i] = As + idx * 8;
    lB[i] = Bs + idx * 8;
  }

  int aoff[4], boff[4];
#pragma unroll
  for (int i = 0; i < 4; ++i) {
    int ra = wm * 64 + i * 16 + r16;
    aoff[i] = ra * 64 + ((quad ^ (ra & 7)) << 3);
    int rb = wn * 64 + i * 16 + r16;
    boff[i] = rb * 64 + ((quad ^ (rb & 7)) << 3);
  }

  f32x4 acc[4][4];
#pragma unroll
  for (int i = 0; i < 4; ++i)
#pragma unroll
    for (int j = 0; j < 4; ++j) acc[i][j] = (f32x4){0.f, 0.f, 0.f, 0.f};

#define STAGE1(kt, b) do { const int ko_ = (kt) << 6; const int lo_ = (b) * 8192;        \
    _Pragma("unroll")                                                                    \
    for (int i_ = 0; i_ < 4; ++i_) gl2lds16(gA[i_] + ko_, lA[i_] + lo_);                 \
    _Pragma("unroll")                                                                    \
    for (int i_ = 0; i_ < 4; ++i_) gl2lds16(gB[i_] + ko_, lB[i_] + lo_); } while (0)

#define COMP1(b) do { const int lo_ = (b) * 8192;                                        \
    _Pragma("unroll")                                                                    \
    for (int g_ = 0; g_ < 2; ++g_) {                                                     \
      const int gx_ = g_ << 5;                                                           \
      bf16x8 av_[4], bv_[4];                                                             \
      _Pragma("unroll")                                                                  \
      for (int i_ = 0; i_ < 4; ++i_) av_[i_] = *(const bf16x8*)(As + lo_ + (aoff[i_] ^ gx_)); \
      _Pragma("unroll")                                                                  \
      for (int j_ = 0; j_ < 4; ++j_) bv_[j_] = *(const bf16x8*)(Bs + lo_ + (boff[j_] ^ gx_)); \
      _Pragma("unroll")                                                                  \
      for (int i_ = 0; i_ < 4; ++i_)                                                     \
        _Pragma("unroll")                                                                \
        for (int j_ = 0; j_ < 4; ++j_)                                                   \
          acc[i_][j_] = __builtin_amdgcn_mfma_f32_16x16x32_bf16(av_[i_], bv_[j_], acc[i_][j_], 0, 0, 0); \
    } } while (0)

  STAGE1(0, 0);
#pragma unroll 1
  for (int kt = 0; kt < 16; kt += 2) {
    if (kt + 1 < 16) { STAGE1(kt + 1, 1); VM8; } else { VM0; }
    barx();
    COMP1(0);
    barx();
    if (kt + 2 < 16) { STAGE1(kt + 2, 0); VM8; } else { VM0; }
    barx();
    COMP1(1);
    barx();
  }
#undef STAGE1
#undef COMP1

  // epilogue: relu(acc+b)*scale, scale = w1/w2/1 by nn
  __syncthreads();
  float* wl = (float*)As;
  if (tid < 128) {
    int tok = perm[eoff + min(tid, valid - 1)];
    float sc = 1.0f;
    if (nn == 0) sc = wpair[tok].x;
    else if (nn == 1) sc = wpair[tok].y;
    wl[tid] = sc;
  }
  __syncthreads();
#pragma unroll
  for (int j = 0; j < 4; ++j) {
    const int cin = wn * 64 + j * 16 + r16;
    const float bz = bias1[brow + cin];
#pragma unroll
    for (int i = 0; i < 4; ++i) {
#pragma unroll
      for (int r = 0; r < 4; ++r) {
        const int lrow = wm * 64 + i * 16 + quad * 4 + r;
        float v = fmaxf(acc[i][j][r] + bz, 0.f) * wl[lrow];
        Hbuf[(size_t)(hbase + lrow) * NH + nn * 128 + cin] = f2bf(v);
      }
    }
  }
}

// ---------------- G2: grouped fc2: [128 tokens] x [128 h-cols], K=768, scatter out ----------------
__global__ __launch_bounds__(256) void moe_fc2(const unsigned short* __restrict__ Hbuf,
                                               const unsigned short* __restrict__ W2cat,
                                               const int* __restrict__ perm,
                                               const float2* __restrict__ wpair,
                                               const float* __restrict__ b2,
                                               const float* __restrict__ bs2,
                                               const int4* __restrict__ tiletab,
                                               const int* __restrict__ ntct,
                                               float* __restrict__ out) {
  const int L   = blockIdx.x;
  const int xcd = L & 7;
  const int s   = L >> 3;
  const int mg  = s >> 3;
  const int nn  = s & 7;
  const int mt  = xcd + (mg << 3);
  if (mt >= ntct[0]) return;
  const int4 tt = tiletab[mt];
  const int eoff = tt.y, valid = tt.z, hbase = tt.w;
  int ef = 0, rem = tt.x;
  while (rem >= 7 - ef) { rem -= 7 - ef; ef++; }
  const int es = ef + 1 + rem;
  const int tileN = nn << 7;

  __shared__ __align__(16) unsigned short As[2 * 128 * 64];
  __shared__ __align__(16) unsigned short Bs[2 * 128 * 64];

  const int tid  = threadIdx.x;
  const int lane = tid & 63;
  const int wv   = tid >> 6;
  const int wm   = wv >> 1;
  const int wn   = wv & 1;
  const int r16  = lane & 15;
  const int quad = lane >> 4;

  const unsigned short* gA[4];
  const unsigned short* gB[4];
  unsigned short* lA[4];
  unsigned short* lB[4];
#pragma unroll
  for (int i = 0; i < 4; ++i) {
    int idx = i * 256 + tid;
    int row = idx >> 3;
    int cc  = idx & 7;
    int kc  = cc ^ (row & 7);
    gA[i] = Hbuf + (size_t)(hbase + row) * NH + kc * 8;
    gB[i] = W2cat + (size_t)(tileN + row) * KC2 + kc * 8;
    lA[i] = As + idx * 8;
    lB[i] = Bs + idx * 8;
  }

  int aoff[4], boff[4];
#pragma unroll
  for (int i = 0; i < 4; ++i) {
    int ra = wm * 64 + i * 16 + r16;
    aoff[i] = ra * 64 + ((quad ^ (ra & 7)) << 3);
    int rb = wn * 64 + i * 16 + r16;
    boff[i] = rb * 64 + ((quad ^ (rb & 7)) << 3);
  }

  f32x4 acc[4][4];
#pragma unroll
  for (int i = 0; i < 4; ++i)
#pragma unroll
    for (int j = 0; j < 4; ++j) acc[i][j] = (f32x4){0.f, 0.f, 0.f, 0.f};

#define KOB2(kt) ((kt) < 2 ? ef * 128 + ((kt) << 6)                       \
                : (kt) < 4 ? es * 128 + (((kt) - 2) << 6)                 \
                           : 1024 + (((kt) - 4) << 6))
#define STAGE2(kt, b) do { const int koA_ = (kt) << 6; const int koB_ = KOB2(kt);        \
    const int lo_ = (b) * 8192;                                                          \
    _Pragma("unroll")                                                                    \
    for (int i_ = 0; i_ < 4; ++i_) gl2lds16(gA[i_] + koA_, lA[i_] + lo_);                \
    _Pragma("unroll")                                                                    \
    for (int i_ = 0; i_ < 4; ++i_) gl2lds16(gB[i_] + koB_, lB[i_] + lo_); } while (0)

#define COMP2(b) do { const int lo_ = (b) * 8192;                                        \
    _Pragma("unroll")                                                                    \
    for (int g_ = 0; g_ < 2; ++g_) {                                                     \
      const int gx_ = g_ << 5;                                                           \
      bf16x8 av_[4], bv_[4];                                                             \
      _Pragma("unroll")                                                                  \
      for (int i_ = 0; i_ < 4; ++i_) av_[i_] = *(const bf16x8*)(As + lo_ + (aoff[i_] ^ gx_)); \
      _Pragma("unroll")                                                                  \
      for (int j_ = 0; j_ < 4; ++j_) bv_[j_] = *(const bf16x8*)(Bs + lo_ + (boff[j_] ^ gx_)); \
      _Pragma("unroll")                                                                  \
      for (int i_ = 0; i_ < 4; ++i_)                                                     \
        _Pragma("unroll")                                                                \
        for (int j_ = 0; j_ < 4; ++j_)                                                   \
          acc[i_][j_] = __builtin_amdgcn_mfma_f32_16x16x32_bf16(av_[i_], bv_[j_], acc[i_][j_], 0, 0, 0); \
    } } while (0)

  STAGE2(0, 0);
#pragma unroll 1
  for (int kt = 0; kt < 12; kt += 2) {
    if (kt + 1 < 12) { STAGE2(kt + 1, 1); VM8; } else { VM0; }
    barx();
    COMP2(0);
    barx();
    if (kt + 2 < 12) { STAGE2(kt + 2, 0); VM8; } else { VM0; }
    barx();
    COMP2(1);
    barx();
  }
#undef STAGE2
#undef COMP2
#undef KOB2

  // epilogue: + bs2 + w1*b2[e1] + w2*b2[e2], scatter to out[token]
  __syncthreads();
  float2* wl2 = (float2*)As;
  int* tokl   = (int*)Bs;
  if (tid < 128) {
    int tokc = perm[eoff + min(tid, valid - 1)];
    tokl[tid] = (tid < valid) ? tokc : -1;
    wl2[tid] = wpair[tokc];
  }
  __syncthreads();
  float bsc[4], b2a[4], b2b[4];
#pragma unroll
  for (int j = 0; j < 4; ++j) {
    const int col = tileN + wn * 64 + j * 16 + r16;
    bsc[j] = bs2[col];
    b2a[j] = b2[(size_t)ef * HD + col];
    b2b[j] = b2[(size_t)es * HD + col];
  }
#pragma unroll
  for (int i = 0; i < 4; ++i) {
#pragma unroll
    for (int r = 0; r < 4; ++r) {
      const int lrow = wm * 64 + i * 16 + quad * 4 + r;
      const int tok = tokl[lrow];
      if (tok < 0) continue;
      const float2 w = wl2[lrow];
#pragma unroll
      for (int j = 0; j < 4; ++j) {
        const int col = tileN + wn * 64 + j * 16 + r16;
        out[(size_t)tok * HD + col] = acc[i][j][r] + bsc[j] + w.x * b2a[j] + w.y * b2b[j];
      }
    }
  }
}

extern "C" void kernel_launch(void* const* d_in, const int* in_sizes, int n_in,
                              void* d_out, int out_size, void* d_ws, size_t ws_size,
                              hipStream_t stream) {
  const float* x   = (const float*)d_in[0];
  const float* Wg  = (const float*)d_in[1];
  const float* W1  = (const float*)d_in[2];
  const float* b1  = (const float*)d_in[3];
  const float* W2  = (const float*)d_in[4];
  const float* b2  = (const float*)d_in[5];
  const float* Ws1 = (const float*)d_in[6];
  const float* bs1 = (const float*)d_in[7];
  const float* Ws2 = (const float*)d_in[8];
  const float* bs2 = (const float*)d_in[9];

  char* ws = (char*)d_ws;
  size_t off = 0;
  unsigned short* xbf   = (unsigned short*)(ws + off); off += (size_t)TTOK * HD * 2;       // 32 MiB
  unsigned short* Hbuf  = (unsigned short*)(ws + off); off += (size_t)MAXT * 128 * NH * 2; // 30 MiB
  unsigned short* W1cat = (unsigned short*)(ws + off); off += (size_t)NC1 * HD * 2;
  unsigned short* W2cat = (unsigned short*)(ws + off); off += (size_t)HD * KC2 * 2;
  float* bias1          = (float*)(ws + off);          off += (size_t)NC1 * 4;
  float2* wpair         = (float2*)(ws + off);         off += (size_t)TTOK * 8;
  int* pid              = (int*)(ws + off);            off += (size_t)TTOK * 4;
  int* perm             = (int*)(ws + off);            off += (size_t)TTOK * 4;
  int4* tiletab         = (int4*)(ws + off);           off += (size_t)MAXT * 16;
  int* ntct             = (int*)(ws + off);            off += 16;

  prep_gate<<<PREPB + GATEB, 256, 0, stream>>>(x, Wg, W1, Ws1, W2, Ws2, b1, bs1,
                                               W1cat, W2cat, bias1, xbf, wpair, pid);
  route_scan<<<NPAIR, 256, 0, stream>>>(pid, perm, tiletab, ntct);
  moe_fc1<<<8 * 20 * 6, 256, 0, stream>>>(xbf, W1cat, perm, wpair, bias1, tiletab, ntct, Hbuf);
  moe_fc2<<<8 * 20 * 8, 256, 0, stream>>>(Hbuf, W2cat, perm, wpair, b2, bs2, tiletab, ntct,
                                          (float*)d_out);
}